// Round 3
// baseline (202.048 us; speedup 1.0000x reference)
//
#include <hip/hip_runtime.h>

// SynthMorphLoss: soft-dice over int32 label maps + diffusion regularizer.
// B=1, D=160, H=192, W=224, 26 classes (class 0 ignored in dice mean).
// R9 == R8 minus the done-ticket (suspected container-killer; unverified
// ws_size assumption + new sync primitive). Finalize back to its own tiny
// dispatch. Main theory under test stays: R7 counters (VALUBusy 9.6%, HBM
// 17%, VGPR 52) => diff path latency-bound with zero prefetch latitude.
// Fix: DCH 5->2, fully flat body, ~20 independent 16B loads in flight per
// wave before any compute (Little's law), 2.5x more diff waves. Bytes +22%
// (irrelevant at 17% HBM).

namespace {
constexpr int NC    = 26;
constexpr int Dd    = 160, Hh = 192, Ww = 224;
constexpr int W4    = Ww / 4;                 // 56 float4 per row
constexpr int PL4   = Hh * W4;                // 10752 float4 per (c,d) plane
constexpr int N4L   = Dd * Hh * Ww / 4;       // 1,720,320 int4 per label map
constexpr int JSTRIDE = 33;                   // joint-hist row stride
constexpr int NBINS   = NC * JSTRIDE;         // 858
constexpr int HIST_BLOCKS = 840;              // 840*256*8 == N4L exact
constexpr int HT          = HIST_BLOCKS * 256;
// diff decomposition: wave owns (c, 6-row h-slab, 2-plane d-chunk)
constexpr int SLAB    = 6;                    // rows per wave
constexpr int SLABS   = Hh / SLAB;            // 32
constexpr int SGRPS   = SLABS / 4;            // 8 slab-groups (4 waves/block)
constexpr int DCH     = 2;                    // d-steps per wave (flat body)
constexpr int DCHUNKS = Dd / DCH;             // 80
constexpr int DIFF_BLOCKS = 3 * DCHUNKS * SGRPS;   // 1920
// fused grid: interleave groups of 8 blocks (one XCD round), pattern d,d,h.
constexpr int GRP       = 8;
constexpr int TRIPLES   = HIST_BLOCKS / GRP;       // 105
constexpr int PAT_GRPS  = 3 * TRIPLES;             // 315 (210 diff + 105 hist)
constexpr int FUSED_BLOCKS = DIFF_BLOCKS + HIST_BLOCKS;  // 2760 == 345*8
}

__global__ void init_ws_kernel(unsigned int* __restrict__ joint,
                               double* __restrict__ sums) {
    int i = blockIdx.x * blockDim.x + threadIdx.x;
    if (i < NBINS) joint[i] = 0u;
    if (i < 3)     sums[i]  = 0.0;
}

// ---- hist path (identical to R6/R7 body) ----
__device__ __forceinline__ void hist_path(
        int hb,
        const int4* __restrict__ f4,
        const int4* __restrict__ m4,
        unsigned int* __restrict__ gj) {
    __shared__ unsigned int h[NBINS];
    for (int i = threadIdx.x; i < NBINS; i += 256) h[i] = 0u;
    __syncthreads();

    const int g = hb * 256 + threadIdx.x;
    int4 a0 = f4[g];
    int4 a1 = f4[g + HT];
    int4 a2 = f4[g + 2 * HT];
    int4 a3 = f4[g + 3 * HT];
    int4 a4 = f4[g + 4 * HT];
    int4 a5 = f4[g + 5 * HT];
    int4 a6 = f4[g + 6 * HT];
    int4 a7 = f4[g + 7 * HT];
    int4 b0 = m4[g];
    int4 b1 = m4[g + HT];
    int4 b2 = m4[g + 2 * HT];
    int4 b3 = m4[g + 3 * HT];
    int4 b4 = m4[g + 4 * HT];
    int4 b5 = m4[g + 5 * HT];
    int4 b6 = m4[g + 6 * HT];
    int4 b7 = m4[g + 7 * HT];

#define JACC(A, B)                                   \
    atomicAdd(&h[(A).x * JSTRIDE + (B).x], 1u);      \
    atomicAdd(&h[(A).y * JSTRIDE + (B).y], 1u);      \
    atomicAdd(&h[(A).z * JSTRIDE + (B).z], 1u);      \
    atomicAdd(&h[(A).w * JSTRIDE + (B).w], 1u);
    JACC(a0, b0) JACC(a1, b1) JACC(a2, b2) JACC(a3, b3)
    JACC(a4, b4) JACC(a5, b5) JACC(a6, b6) JACC(a7, b7)
#undef JACC

    __syncthreads();
    for (int i = threadIdx.x; i < NBINS; i += 256) {
        unsigned int v = h[i];
        if (v) atomicAdd(&gj[i], v);
    }
}

// ---- diff path: flat 2-step body, one up-front independent load cluster ----
// Wave owns (c, 6-row h-slab, planes d0 & d0+1). Loads: plane d0 rows+halo,
// plane d0+1 rows+halo, plane d0+2 rows (for the second dz). ~20 independent
// 16B loads in flight before any compute.
__device__ __forceinline__ void diff_path(
        int db,
        const float4* __restrict__ v4,
        double* __restrict__ gs) {
    const int lane = threadIdx.x & 63;
    const int wid  = threadIdx.x >> 6;
    const int c      = db / (DCHUNKS * SGRPS);    // db / 640
    const int rem    = db % (DCHUNKS * SGRPS);
    const int dchunk = rem / SGRPS;
    const int sgrp   = rem % SGRPS;
    const int slab   = sgrp * 4 + wid;
    const int h0     = slab * SLAB;
    const int d0     = dchunk * DCH;
    const bool al    = (lane < W4);
    const bool hv    = (h0 + SLAB < Hh);          // dy-halo row exists
    const int  l     = al ? lane : (W4 - 1);      // clamp inactive lanes
    const bool dz1   = (d0 + 1 < Dd - 1);         // second dz step valid
                                                  // (false only for d0 == 158)

    const size_t base = ((size_t)(c * Dd + d0) * Hh + h0) * W4 + l;
    const int haloOff = (hv ? SLAB : SLAB - 1) * W4;   // clamp: masked anyway

    // plane d0
    float4 a0 = v4[base];
    float4 a1 = v4[base + W4];
    float4 a2 = v4[base + 2 * W4];
    float4 a3 = v4[base + 3 * W4];
    float4 a4 = v4[base + 4 * W4];
    float4 a5 = v4[base + 5 * W4];
    float4 hA = v4[base + haloOff];
    // plane d0+1 (always exists: d0 <= 158)
    const size_t bb = base + PL4;
    float4 b0 = v4[bb];
    float4 b1 = v4[bb + W4];
    float4 b2 = v4[bb + 2 * W4];
    float4 b3 = v4[bb + 3 * W4];
    float4 b4 = v4[bb + 4 * W4];
    float4 b5 = v4[bb + 5 * W4];
    float4 hB = v4[bb + haloOff];
    // plane d0+2 (only if second dz valid) — loads issued early, used last
    float4 q0, q1, q2, q3, q4, q5;
    if (dz1) {
        const size_t cc = bb + PL4;
        q0 = v4[cc];
        q1 = v4[cc + W4];
        q2 = v4[cc + 2 * W4];
        q3 = v4[cc + 3 * W4];
        q4 = v4[cc + 4 * W4];
        q5 = v4[cc + 5 * W4];
    } else {
        q0 = b0; q1 = b1; q2 = b2; q3 = b3; q4 = b4; q5 = b5;
    }

    float sx = 0.f, sy = 0.f, sz = 0.f;

#define DX(P)                                                                  \
    {                                                                          \
        float d1 = (P).y - (P).x, d2 = (P).z - (P).y, d3 = (P).w - (P).z;      \
        sx += d1 * d1 + d2 * d2 + d3 * d3;                                     \
        float nx = __shfl_down((P).x, 1);                                      \
        float d4 = nx - (P).w;                                                 \
        sx += (lane < W4 - 1) ? d4 * d4 : 0.f;                                 \
    }
#define DY(A, B)                                                               \
    {                                                                          \
        float e0 = (B).x - (A).x, e1 = (B).y - (A).y;                          \
        float e2 = (B).z - (A).z, e3 = (B).w - (A).w;                          \
        sy += e0 * e0 + e1 * e1 + e2 * e2 + e3 * e3;                           \
    }
#define DZ(A, B)                                                               \
    {                                                                          \
        float e0 = (B).x - (A).x, e1 = (B).y - (A).y;                          \
        float e2 = (B).z - (A).z, e3 = (B).w - (A).w;                          \
        sz += e0 * e0 + e1 * e1 + e2 * e2 + e3 * e3;                           \
    }
    // k = 0 (plane d0): dx, dy, dz vs plane d0+1 (always valid, d0 <= 158)
    DX(a0) DX(a1) DX(a2) DX(a3) DX(a4) DX(a5)
    DY(a0, a1) DY(a1, a2) DY(a2, a3) DY(a3, a4) DY(a4, a5)
    if (hv) DY(a5, hA)
    DZ(a0, b0) DZ(a1, b1) DZ(a2, b2) DZ(a3, b3) DZ(a4, b4) DZ(a5, b5)
    // k = 1 (plane d0+1): dx, dy, dz vs plane d0+2 (if valid)
    DX(b0) DX(b1) DX(b2) DX(b3) DX(b4) DX(b5)
    DY(b0, b1) DY(b1, b2) DY(b2, b3) DY(b3, b4) DY(b4, b5)
    if (hv) DY(b5, hB)
    if (dz1) {
        DZ(b0, q0) DZ(b1, q1) DZ(b2, q2) DZ(b3, q3) DZ(b4, q4) DZ(b5, q5)
    }
#undef DX
#undef DY
#undef DZ

    if (!al) { sx = 0.f; sy = 0.f; sz = 0.f; }    // clamped lanes: drop dupes

    #pragma unroll
    for (int off = 32; off > 0; off >>= 1) {
        sx += __shfl_down(sx, off);
        sy += __shfl_down(sy, off);
        sz += __shfl_down(sz, off);
    }
    __shared__ float px[4], py[4], pz[4];
    if (lane == 0) { px[wid] = sx; py[wid] = sy; pz[wid] = sz; }
    __syncthreads();
    if (threadIdx.x == 0) {
        atomicAdd(&gs[0], (double)(px[0] + px[1] + px[2] + px[3]));
        atomicAdd(&gs[1], (double)(py[0] + py[1] + py[2] + py[3]));
        atomicAdd(&gs[2], (double)(pz[0] + pz[1] + pz[2] + pz[3]));
    }
}

// Fused dispatch: groups of 8 consecutive blocks; pattern diff,diff,hist per
// triple (ratio 1920:840), diff tail at the end.
__global__ __launch_bounds__(256, 4) void fused_kernel(
        const int4* __restrict__ f4,
        const int4* __restrict__ m4,
        unsigned int* __restrict__ gj,
        const float4* __restrict__ v4,
        double* __restrict__ gs) {
    const int grp = blockIdx.x >> 3;
    const int t   = blockIdx.x & 7;
    if (grp < PAT_GRPS) {
        const int tri = grp / 3;
        const int r   = grp - tri * 3;
        if (r == 2) hist_path(tri * GRP + t, f4, m4, gj);
        else        diff_path((tri * 2 + r) * GRP + t, v4, gs);
    } else {
        diff_path((2 * TRIPLES + (grp - PAT_GRPS)) * GRP + t, v4, gs);
    }
}

__global__ void finalize_kernel(const unsigned int* __restrict__ gj,
                                const double* __restrict__ gs,
                                float* __restrict__ out) {
    int lane = threadIdx.x & 63;
    float term = 0.f;
    if (lane >= 1 && lane < NC) {
        float fv = 0.f, mv = 0.f;
        #pragma unroll
        for (int m = 0; m < NC; ++m) fv += (float)gj[lane * JSTRIDE + m];
        #pragma unroll
        for (int f = 0; f < NC; ++f) mv += (float)gj[f * JSTRIDE + lane];
        float iv = (float)gj[lane * JSTRIDE + lane];
        term = (2.f * iv + 1e-5f) / (fv + mv + 1e-5f);
    }
    #pragma unroll
    for (int off = 32; off > 0; off >>= 1) term += __shfl_down(term, off);
    if (threadIdx.x == 0 && blockIdx.x == 0) {
        float sim = 1.f - term * (1.f / 25.f);
        double mdx = gs[0] / ((double)3 * Dd * Hh * (Ww - 1));
        double mdy = gs[1] / ((double)3 * Dd * (Hh - 1) * Ww);
        double mdz = gs[2] / ((double)3 * (Dd - 1) * Hh * Ww);
        float smooth = (float)((mdx + mdy + mdz) / 3.0);
        out[0] = sim + smooth;
        out[1] = sim;
        out[2] = smooth;
    }
}

extern "C" void kernel_launch(void* const* d_in, const int* in_sizes, int n_in,
                              void* d_out, int out_size, void* d_ws, size_t ws_size,
                              hipStream_t stream) {
    const int*   fl = (const int*)d_in[0];
    const int*   ml = (const int*)d_in[1];
    const float* vf = (const float*)d_in[2];
    float* out = (float*)d_out;

    // workspace: [0, 3432) joint counts (858 uints); [3584, 3608) double sums[3]
    unsigned int* joint = (unsigned int*)d_ws;
    double*       sums  = (double*)((char*)d_ws + 3584);

    init_ws_kernel<<<1, 1024, 0, stream>>>(joint, sums);
    fused_kernel<<<FUSED_BLOCKS, 256, 0, stream>>>(
        (const int4*)fl, (const int4*)ml, joint, (const float4*)vf, sums);
    finalize_kernel<<<1, 64, 0, stream>>>(joint, sums, out);
}

// Round 4
// 176.199 us; speedup vs baseline: 1.1467x; 1.1467x over previous
//
#include <hip/hip_runtime.h>

// SynthMorphLoss: soft-dice over int32 label maps + diffusion regularizer.
// B=1, D=160, H=192, W=224, 26 classes (class 0 ignored in dice mean).
// R10: per-block dispatch-overhead theory. R7(1608 blk)=60.9us=37.9ns/blk,
// R9(2760 blk)=84.2us=30.5ns/blk => T ~ Nblocks * ~30ns dominates; CUs are
// starved (VALUBusy<10%, ~1.7 outstanding wave-loads/CU). Fix: SAME per-wave
// work as R7 (proven z-carry DCH=5 diff + hist bodies), packed into
// 1024-thread blocks: 402 blocks total (192 diff + 210 hist). Interleave
// types in runs of 8 consecutive blocks (one XCD round-robin cycle) so both
// types cover all 8 XCDs; block-parity would segregate types onto even/odd
// XCDs (XCD = blockIdx % 8).

namespace {
constexpr int NC    = 26;
constexpr int Dd    = 160, Hh = 192, Ww = 224;
constexpr int W4    = Ww / 4;                 // 56 float4 per row
constexpr int PL4   = Hh * W4;                // 10752 float4 per (c,d) plane
constexpr int N4L   = Dd * Hh * Ww / 4;       // 1,720,320 int4 per label map
constexpr int JSTRIDE = 33;                   // joint-hist row stride
constexpr int NBINS   = NC * JSTRIDE;         // 858
constexpr int TPB     = 1024;                 // 16 waves per block
constexpr int WPB     = TPB / 64;             // 16
// hist: 210 blocks x 1024 threads x 8 int4 per map (exact: 210*1024*8 == N4L)
constexpr int HIST_BLOCKS = 210;
constexpr int HT          = HIST_BLOCKS * TPB;     // 215040
// diff: wave owns (c, 6-row h-slab, 5-plane d-chunk) — R7 body verbatim
constexpr int SLAB    = 6;                    // rows per wave
constexpr int DCH     = 5;                    // d-steps per wave
constexpr int DIFF_WAVES  = 3 * (Dd / DCH) * (Hh / SLAB);  // 3072
constexpr int DIFF_BLOCKS = DIFF_WAVES / WPB;              // 192
constexpr int FUSED_BLOCKS = DIFF_BLOCKS + HIST_BLOCKS;    // 402
// groups of 8 blocks: even group -> diff, odd group -> hist, tail hist.
constexpr int GRP         = 8;
constexpr int DIFF_GRPS   = DIFF_BLOCKS / GRP;   // 24
constexpr int PAIRED_GRPS = 2 * DIFF_GRPS;       // 48 -> blocks [0,384)
}

__global__ void init_ws_kernel(unsigned int* __restrict__ joint,
                               double* __restrict__ sums) {
    int i = blockIdx.x * blockDim.x + threadIdx.x;
    if (i < NBINS) joint[i] = 0u;
    if (i < 3)     sums[i]  = 0.0;
}

// ---- hist path: same per-thread work as R6/R7 (8 int4 per map) ----
__device__ __forceinline__ void hist_path(
        int hb,
        const int4* __restrict__ f4,
        const int4* __restrict__ m4,
        unsigned int* __restrict__ gj) {
    __shared__ unsigned int h[NBINS];
    for (int i = threadIdx.x; i < NBINS; i += TPB) h[i] = 0u;
    __syncthreads();

    const int g = hb * TPB + threadIdx.x;
    int4 a0 = f4[g];
    int4 a1 = f4[g + HT];
    int4 a2 = f4[g + 2 * HT];
    int4 a3 = f4[g + 3 * HT];
    int4 a4 = f4[g + 4 * HT];
    int4 a5 = f4[g + 5 * HT];
    int4 a6 = f4[g + 6 * HT];
    int4 a7 = f4[g + 7 * HT];
    int4 b0 = m4[g];
    int4 b1 = m4[g + HT];
    int4 b2 = m4[g + 2 * HT];
    int4 b3 = m4[g + 3 * HT];
    int4 b4 = m4[g + 4 * HT];
    int4 b5 = m4[g + 5 * HT];
    int4 b6 = m4[g + 6 * HT];
    int4 b7 = m4[g + 7 * HT];

#define JACC(A, B)                                   \
    atomicAdd(&h[(A).x * JSTRIDE + (B).x], 1u);      \
    atomicAdd(&h[(A).y * JSTRIDE + (B).y], 1u);      \
    atomicAdd(&h[(A).z * JSTRIDE + (B).z], 1u);      \
    atomicAdd(&h[(A).w * JSTRIDE + (B).w], 1u);
    JACC(a0, b0) JACC(a1, b1) JACC(a2, b2) JACC(a3, b3)
    JACC(a4, b4) JACC(a5, b5) JACC(a6, b6) JACC(a7, b7)
#undef JACC

    __syncthreads();
    for (int i = threadIdx.x; i < NBINS; i += TPB) {
        unsigned int v = h[i];
        if (v) atomicAdd(&gj[i], v);
    }
}

// ---- diff path: R7 z-carry body verbatim; wave id from (block, wid) ----
// Wave w: c = w/1024, dchunk = (w%1024)/32, slab = w%32.
// Carries current plane's 6 rows in registers (dz free); per d-step loads
// next plane's 6 rows + 1 dy-halo row. Next-plane loads overlap current
// compute (software pipeline the compiler preserved at 52-64 VGPR).
__device__ __forceinline__ void diff_path(
        int db,
        const float4* __restrict__ v4,
        double* __restrict__ gs) {
    const int lane = threadIdx.x & 63;
    const int wid  = threadIdx.x >> 6;
    const int w      = db * WPB + wid;
    const int c      = w >> 10;
    const int rem    = w & 1023;
    const int dchunk = rem >> 5;
    const int slab   = rem & 31;
    const int h0     = slab * SLAB;
    const int d0     = dchunk * DCH;
    const bool al    = (lane < W4);
    const bool hv    = (h0 + SLAB < Hh);          // dy-halo row exists
    const int  l     = al ? lane : (W4 - 1);      // clamp inactive lanes

    size_t cur = ((size_t)(c * Dd + d0) * Hh + h0) * W4 + l;

    float4 p0 = v4[cur];
    float4 p1 = v4[cur + W4];
    float4 p2 = v4[cur + 2 * W4];
    float4 p3 = v4[cur + 3 * W4];
    float4 p4 = v4[cur + 4 * W4];
    float4 p5 = v4[cur + 5 * W4];

    float sx = 0.f, sy = 0.f, sz = 0.f;
    const int haloOff = (hv ? SLAB : SLAB - 1) * W4;   // clamp: masked anyway

    for (int k = 0; k < DCH; ++k) {
        const int d = d0 + k;
        const bool dzv = (d < Dd - 1);            // wave-uniform
        float4 hl = v4[cur + haloOff];
        float4 n0 = p0, n1 = p1, n2 = p2, n3 = p3, n4 = p4, n5 = p5;
        if (dzv) {
            const size_t nb = cur + PL4;
            n0 = v4[nb];
            n1 = v4[nb + W4];
            n2 = v4[nb + 2 * W4];
            n3 = v4[nb + 3 * W4];
            n4 = v4[nb + 4 * W4];
            n5 = v4[nb + 5 * W4];
        }

        // dx: 3 interior diffs + crossing diff (lane mask)
#define DX(P)                                                                  \
        {                                                                      \
            float d1 = (P).y - (P).x, d2 = (P).z - (P).y, d3 = (P).w - (P).z;  \
            sx += d1 * d1 + d2 * d2 + d3 * d3;                                 \
            float nx = __shfl_down((P).x, 1);                                  \
            float d4 = nx - (P).w;                                             \
            sx += (lane < W4 - 1) ? d4 * d4 : 0.f;                             \
        }
        DX(p0) DX(p1) DX(p2) DX(p3) DX(p4) DX(p5)
#undef DX
        // dy: rows 0..4 within slab; row 5 against halo (wave-uniform hv)
#define DY(A, B)                                                               \
        {                                                                      \
            float e0 = (B).x - (A).x, e1 = (B).y - (A).y;                      \
            float e2 = (B).z - (A).z, e3 = (B).w - (A).w;                      \
            sy += e0 * e0 + e1 * e1 + e2 * e2 + e3 * e3;                       \
        }
        DY(p0, p1) DY(p1, p2) DY(p2, p3) DY(p3, p4) DY(p4, p5)
        if (hv) DY(p5, hl)
#undef DY
        // dz: next plane minus current (registers), wave-uniform dzv
        if (dzv) {
#define DZ(A, B)                                                               \
            {                                                                  \
                float e0 = (B).x - (A).x, e1 = (B).y - (A).y;                  \
                float e2 = (B).z - (A).z, e3 = (B).w - (A).w;                  \
                sz += e0 * e0 + e1 * e1 + e2 * e2 + e3 * e3;                   \
            }
            DZ(p0, n0) DZ(p1, n1) DZ(p2, n2) DZ(p3, n3) DZ(p4, n4) DZ(p5, n5)
#undef DZ
        }
        p0 = n0; p1 = n1; p2 = n2; p3 = n3; p4 = n4; p5 = n5;
        cur += PL4;
    }

    if (!al) { sx = 0.f; sy = 0.f; sz = 0.f; }    // clamped lanes: drop dupes

    #pragma unroll
    for (int off = 32; off > 0; off >>= 1) {
        sx += __shfl_down(sx, off);
        sy += __shfl_down(sy, off);
        sz += __shfl_down(sz, off);
    }
    __shared__ float px[WPB], py[WPB], pz[WPB];
    if (lane == 0) { px[wid] = sx; py[wid] = sy; pz[wid] = sz; }
    __syncthreads();
    if (threadIdx.x == 0) {
        float tx = 0.f, ty = 0.f, tz = 0.f;
        #pragma unroll
        for (int i = 0; i < WPB; ++i) { tx += px[i]; ty += py[i]; tz += pz[i]; }
        atomicAdd(&gs[0], (double)tx);
        atomicAdd(&gs[1], (double)ty);
        atomicAdd(&gs[2], (double)tz);
    }
}

// 402 blocks of 1024 threads. Groups of 8 consecutive blocks (one XCD
// round-robin cycle): even group -> diff, odd group -> hist, tail hist.
__global__ __launch_bounds__(1024, 4) void fused_kernel(
        const int4* __restrict__ f4,
        const int4* __restrict__ m4,
        unsigned int* __restrict__ gj,
        const float4* __restrict__ v4,
        double* __restrict__ gs) {
    const int grp = blockIdx.x >> 3;
    const int t   = blockIdx.x & 7;
    if (grp < PAIRED_GRPS) {
        const int idx = (grp >> 1) * GRP + t;     // 0..191 within each type
        if (grp & 1) hist_path(idx, f4, m4, gj);
        else         diff_path(idx, v4, gs);
    } else {
        // hist tail: ids 192..209 (blocks 384..401)
        hist_path(DIFF_BLOCKS + (blockIdx.x - PAIRED_GRPS * GRP), f4, m4, gj);
    }
}

__global__ void finalize_kernel(const unsigned int* __restrict__ gj,
                                const double* __restrict__ gs,
                                float* __restrict__ out) {
    int lane = threadIdx.x & 63;
    float term = 0.f;
    if (lane >= 1 && lane < NC) {
        float fv = 0.f, mv = 0.f;
        #pragma unroll
        for (int m = 0; m < NC; ++m) fv += (float)gj[lane * JSTRIDE + m];
        #pragma unroll
        for (int f = 0; f < NC; ++f) mv += (float)gj[f * JSTRIDE + lane];
        float iv = (float)gj[lane * JSTRIDE + lane];
        term = (2.f * iv + 1e-5f) / (fv + mv + 1e-5f);
    }
    #pragma unroll
    for (int off = 32; off > 0; off >>= 1) term += __shfl_down(term, off);
    if (threadIdx.x == 0 && blockIdx.x == 0) {
        float sim = 1.f - term * (1.f / 25.f);
        double mdx = gs[0] / ((double)3 * Dd * Hh * (Ww - 1));
        double mdy = gs[1] / ((double)3 * Dd * (Hh - 1) * Ww);
        double mdz = gs[2] / ((double)3 * (Dd - 1) * Hh * Ww);
        float smooth = (float)((mdx + mdy + mdz) / 3.0);
        out[0] = sim + smooth;
        out[1] = sim;
        out[2] = smooth;
    }
}

extern "C" void kernel_launch(void* const* d_in, const int* in_sizes, int n_in,
                              void* d_out, int out_size, void* d_ws, size_t ws_size,
                              hipStream_t stream) {
    const int*   fl = (const int*)d_in[0];
    const int*   ml = (const int*)d_in[1];
    const float* vf = (const float*)d_in[2];
    float* out = (float*)d_out;

    // workspace: [0, 3432) joint counts (858 uints); [3584, 3608) double sums[3]
    unsigned int* joint = (unsigned int*)d_ws;
    double*       sums  = (double*)((char*)d_ws + 3584);

    init_ws_kernel<<<1, 1024, 0, stream>>>(joint, sums);
    fused_kernel<<<FUSED_BLOCKS, 1024, 0, stream>>>(
        (const int4*)fl, (const int4*)ml, joint, (const float4*)vf, sums);
    finalize_kernel<<<1, 64, 0, stream>>>(joint, sums, out);
}

// Round 6
// 175.199 us; speedup vs baseline: 1.1533x; 1.0057x over previous
//
#include <hip/hip_runtime.h>

// SynthMorphLoss: soft-dice over int32 label maps + diffusion regularizer.
// B=1, D=160, H=192, W=224, 26 classes (class 0 ignored in dice mean).
// R12 == R11 resubmitted verbatim (R11 bench died to infra: "container
// failed twice" with no kernel-side hazard class present — no new sync
// primitives, plain dispatches; session has 4 prior infra flakes).
// Dual-chain MLP theory under test: R7(1608blk)==R10(402blk)==60.8us kills
// dispatch-overhead; counters say 4.8 B/cyc/CU = ~2-3 outstanding
// wave-loads/CU, VGPR=52 == exact z-carry live set => zero compiler slack
// to overlap k-steps. Fix: each diff wave runs TWO independent z-carry
// chains (tiles w and w+1536), loop shape verbatim, bodies interleaved =>
// 2x independent load clusters in flight per wave. 512-thr blocks,
// launch_bounds(512,2). Diff blocks first, hist behind.

namespace {
constexpr int NC    = 26;
constexpr int Dd    = 160, Hh = 192, Ww = 224;
constexpr int W4    = Ww / 4;                 // 56 float4 per row
constexpr int PL4   = Hh * W4;                // 10752 float4 per (c,d) plane
constexpr int N4L   = Dd * Hh * Ww / 4;       // 1,720,320 int4 per label map
constexpr int JSTRIDE = 33;                   // joint-hist row stride
constexpr int NBINS   = NC * JSTRIDE;         // 858
constexpr int TPB     = 512;                  // 8 waves per block
constexpr int WPB     = TPB / 64;             // 8
// hist: 420 blocks x 512 threads x 8 int4 per map (420*512*8 == N4L exact)
constexpr int HIST_BLOCKS = 420;
constexpr int HT          = HIST_BLOCKS * TPB;     // 215040
// diff: tile = (c, 6-row h-slab, 5-plane d-chunk); 3072 tiles total.
// Each wave owns TWO tiles: w and w + 1536.
constexpr int SLAB    = 6;                    // rows per tile
constexpr int DCH     = 5;                    // d-steps per tile
constexpr int NTILES  = 3 * (Dd / DCH) * (Hh / SLAB);  // 3072
constexpr int DIFF_WAVES  = NTILES / 2;                // 1536
constexpr int DIFF_BLOCKS = DIFF_WAVES / WPB;          // 192
constexpr int FUSED_BLOCKS = DIFF_BLOCKS + HIST_BLOCKS;  // 612
}

__global__ void init_ws_kernel(unsigned int* __restrict__ joint,
                               double* __restrict__ sums) {
    int i = blockIdx.x * blockDim.x + threadIdx.x;
    if (i < NBINS) joint[i] = 0u;
    if (i < 3)     sums[i]  = 0.0;
}

// ---- hist path: same per-thread work as R6-R10 (8 int4 per map) ----
__device__ __forceinline__ void hist_path(
        int hb,
        const int4* __restrict__ f4,
        const int4* __restrict__ m4,
        unsigned int* __restrict__ gj) {
    __shared__ unsigned int h[NBINS];
    for (int i = threadIdx.x; i < NBINS; i += TPB) h[i] = 0u;
    __syncthreads();

    const int g = hb * TPB + threadIdx.x;
    int4 a0 = f4[g];
    int4 a1 = f4[g + HT];
    int4 a2 = f4[g + 2 * HT];
    int4 a3 = f4[g + 3 * HT];
    int4 a4 = f4[g + 4 * HT];
    int4 a5 = f4[g + 5 * HT];
    int4 a6 = f4[g + 6 * HT];
    int4 a7 = f4[g + 7 * HT];
    int4 b0 = m4[g];
    int4 b1 = m4[g + HT];
    int4 b2 = m4[g + 2 * HT];
    int4 b3 = m4[g + 3 * HT];
    int4 b4 = m4[g + 4 * HT];
    int4 b5 = m4[g + 5 * HT];
    int4 b6 = m4[g + 6 * HT];
    int4 b7 = m4[g + 7 * HT];

#define JACC(A, B)                                   \
    atomicAdd(&h[(A).x * JSTRIDE + (B).x], 1u);      \
    atomicAdd(&h[(A).y * JSTRIDE + (B).y], 1u);      \
    atomicAdd(&h[(A).z * JSTRIDE + (B).z], 1u);      \
    atomicAdd(&h[(A).w * JSTRIDE + (B).w], 1u);
    JACC(a0, b0) JACC(a1, b1) JACC(a2, b2) JACC(a3, b3)
    JACC(a4, b4) JACC(a5, b5) JACC(a6, b6) JACC(a7, b7)
#undef JACC

    __syncthreads();
    for (int i = threadIdx.x; i < NBINS; i += TPB) {
        unsigned int v = h[i];
        if (v) atomicAdd(&gj[i], v);
    }
}

// ---- diff path: TWO independent z-carry chains per wave ----
// Tile t: c = t>>10, dchunk = (t&1023)>>5, slab = t&31.
// Chain bodies are the proven R7/R10 structure, interleaved A/B per k-step.
__device__ __forceinline__ void diff_path(
        int db,
        const float4* __restrict__ v4,
        double* __restrict__ gs) {
    const int lane = threadIdx.x & 63;
    const int wid  = threadIdx.x >> 6;
    const int w    = db * WPB + wid;          // 0..1535
    const bool al  = (lane < W4);
    const int  l   = al ? lane : (W4 - 1);    // clamp inactive lanes

    // tile A
    const int tA = w;
    const int cA = tA >> 10, remA = tA & 1023;
    const int d0A = (remA >> 5) * DCH;
    const int h0A = (remA & 31) * SLAB;
    const bool hvA = (h0A + SLAB < Hh);
    const int hOffA = (hvA ? SLAB : SLAB - 1) * W4;
    size_t curA = ((size_t)(cA * Dd + d0A) * Hh + h0A) * W4 + l;
    // tile B
    const int tB = w + DIFF_WAVES;
    const int cB = tB >> 10, remB = tB & 1023;
    const int d0B = (remB >> 5) * DCH;
    const int h0B = (remB & 31) * SLAB;
    const bool hvB = (h0B + SLAB < Hh);
    const int hOffB = (hvB ? SLAB : SLAB - 1) * W4;
    size_t curB = ((size_t)(cB * Dd + d0B) * Hh + h0B) * W4 + l;

    float4 pA0 = v4[curA];
    float4 pA1 = v4[curA + W4];
    float4 pA2 = v4[curA + 2 * W4];
    float4 pA3 = v4[curA + 3 * W4];
    float4 pA4 = v4[curA + 4 * W4];
    float4 pA5 = v4[curA + 5 * W4];
    float4 pB0 = v4[curB];
    float4 pB1 = v4[curB + W4];
    float4 pB2 = v4[curB + 2 * W4];
    float4 pB3 = v4[curB + 3 * W4];
    float4 pB4 = v4[curB + 4 * W4];
    float4 pB5 = v4[curB + 5 * W4];

    float sx = 0.f, sy = 0.f, sz = 0.f;

#define DX(P)                                                                  \
    {                                                                          \
        float d1 = (P).y - (P).x, d2 = (P).z - (P).y, d3 = (P).w - (P).z;      \
        sx += d1 * d1 + d2 * d2 + d3 * d3;                                     \
        float nx = __shfl_down((P).x, 1);                                      \
        float d4 = nx - (P).w;                                                 \
        sx += (lane < W4 - 1) ? d4 * d4 : 0.f;                                 \
    }
#define DY(A, B)                                                               \
    {                                                                          \
        float e0 = (B).x - (A).x, e1 = (B).y - (A).y;                          \
        float e2 = (B).z - (A).z, e3 = (B).w - (A).w;                          \
        sy += e0 * e0 + e1 * e1 + e2 * e2 + e3 * e3;                           \
    }
#define DZ(A, B)                                                               \
    {                                                                          \
        float e0 = (B).x - (A).x, e1 = (B).y - (A).y;                          \
        float e2 = (B).z - (A).z, e3 = (B).w - (A).w;                          \
        sz += e0 * e0 + e1 * e1 + e2 * e2 + e3 * e3;                           \
    }

    for (int k = 0; k < DCH; ++k) {
        const bool dzvA = (d0A + k < Dd - 1);     // wave-uniform
        const bool dzvB = (d0B + k < Dd - 1);
        // issue BOTH halo loads + BOTH next-plane clusters up front
        float4 hlA = v4[curA + hOffA];
        float4 hlB = v4[curB + hOffB];
        float4 nA0 = pA0, nA1 = pA1, nA2 = pA2, nA3 = pA3, nA4 = pA4, nA5 = pA5;
        if (dzvA) {
            const size_t nb = curA + PL4;
            nA0 = v4[nb];
            nA1 = v4[nb + W4];
            nA2 = v4[nb + 2 * W4];
            nA3 = v4[nb + 3 * W4];
            nA4 = v4[nb + 4 * W4];
            nA5 = v4[nb + 5 * W4];
        }
        float4 nB0 = pB0, nB1 = pB1, nB2 = pB2, nB3 = pB3, nB4 = pB4, nB5 = pB5;
        if (dzvB) {
            const size_t nb = curB + PL4;
            nB0 = v4[nb];
            nB1 = v4[nb + W4];
            nB2 = v4[nb + 2 * W4];
            nB3 = v4[nb + 3 * W4];
            nB4 = v4[nb + 4 * W4];
            nB5 = v4[nb + 5 * W4];
        }

        // chain A compute
        DX(pA0) DX(pA1) DX(pA2) DX(pA3) DX(pA4) DX(pA5)
        DY(pA0, pA1) DY(pA1, pA2) DY(pA2, pA3) DY(pA3, pA4) DY(pA4, pA5)
        if (hvA) DY(pA5, hlA)
        if (dzvA) {
            DZ(pA0, nA0) DZ(pA1, nA1) DZ(pA2, nA2)
            DZ(pA3, nA3) DZ(pA4, nA4) DZ(pA5, nA5)
        }
        // chain B compute
        DX(pB0) DX(pB1) DX(pB2) DX(pB3) DX(pB4) DX(pB5)
        DY(pB0, pB1) DY(pB1, pB2) DY(pB2, pB3) DY(pB3, pB4) DY(pB4, pB5)
        if (hvB) DY(pB5, hlB)
        if (dzvB) {
            DZ(pB0, nB0) DZ(pB1, nB1) DZ(pB2, nB2)
            DZ(pB3, nB3) DZ(pB4, nB4) DZ(pB5, nB5)
        }

        pA0 = nA0; pA1 = nA1; pA2 = nA2; pA3 = nA3; pA4 = nA4; pA5 = nA5;
        pB0 = nB0; pB1 = nB1; pB2 = nB2; pB3 = nB3; pB4 = nB4; pB5 = nB5;
        curA += PL4; curB += PL4;
    }
#undef DX
#undef DY
#undef DZ

    if (!al) { sx = 0.f; sy = 0.f; sz = 0.f; }    // clamped lanes: drop dupes

    #pragma unroll
    for (int off = 32; off > 0; off >>= 1) {
        sx += __shfl_down(sx, off);
        sy += __shfl_down(sy, off);
        sz += __shfl_down(sz, off);
    }
    __shared__ float px[WPB], py[WPB], pz[WPB];
    if (lane == 0) { px[wid] = sx; py[wid] = sy; pz[wid] = sz; }
    __syncthreads();
    if (threadIdx.x == 0) {
        float tx = 0.f, ty = 0.f, tz = 0.f;
        #pragma unroll
        for (int i = 0; i < WPB; ++i) { tx += px[i]; ty += py[i]; tz += pz[i]; }
        atomicAdd(&gs[0], (double)tx);
        atomicAdd(&gs[1], (double)ty);
        atomicAdd(&gs[2], (double)tz);
    }
}

// 612 blocks of 512 threads: diff blocks [0,192) first (long-running,
// dual-chain), hist blocks [192,612) behind them (short, fill in as CUs
// free up). launch_bounds(512,2): 1 block/CU floor, VGPR cap 256 (no spill).
__global__ __launch_bounds__(512, 2) void fused_kernel(
        const int4* __restrict__ f4,
        const int4* __restrict__ m4,
        unsigned int* __restrict__ gj,
        const float4* __restrict__ v4,
        double* __restrict__ gs) {
    if (blockIdx.x < DIFF_BLOCKS) diff_path(blockIdx.x, v4, gs);
    else                          hist_path(blockIdx.x - DIFF_BLOCKS, f4, m4, gj);
}

__global__ void finalize_kernel(const unsigned int* __restrict__ gj,
                                const double* __restrict__ gs,
                                float* __restrict__ out) {
    int lane = threadIdx.x & 63;
    float term = 0.f;
    if (lane >= 1 && lane < NC) {
        float fv = 0.f, mv = 0.f;
        #pragma unroll
        for (int m = 0; m < NC; ++m) fv += (float)gj[lane * JSTRIDE + m];
        #pragma unroll
        for (int f = 0; f < NC; ++f) mv += (float)gj[f * JSTRIDE + lane];
        float iv = (float)gj[lane * JSTRIDE + lane];
        term = (2.f * iv + 1e-5f) / (fv + mv + 1e-5f);
    }
    #pragma unroll
    for (int off = 32; off > 0; off >>= 1) term += __shfl_down(term, off);
    if (threadIdx.x == 0 && blockIdx.x == 0) {
        float sim = 1.f - term * (1.f / 25.f);
        double mdx = gs[0] / ((double)3 * Dd * Hh * (Ww - 1));
        double mdy = gs[1] / ((double)3 * Dd * (Hh - 1) * Ww);
        double mdz = gs[2] / ((double)3 * (Dd - 1) * Hh * Ww);
        float smooth = (float)((mdx + mdy + mdz) / 3.0);
        out[0] = sim + smooth;
        out[1] = sim;
        out[2] = smooth;
    }
}

extern "C" void kernel_launch(void* const* d_in, const int* in_sizes, int n_in,
                              void* d_out, int out_size, void* d_ws, size_t ws_size,
                              hipStream_t stream) {
    const int*   fl = (const int*)d_in[0];
    const int*   ml = (const int*)d_in[1];
    const float* vf = (const float*)d_in[2];
    float* out = (float*)d_out;

    // workspace: [0, 3432) joint counts (858 uints); [3584, 3608) double sums[3]
    unsigned int* joint = (unsigned int*)d_ws;
    double*       sums  = (double*)((char*)d_ws + 3584);

    init_ws_kernel<<<1, 1024, 0, stream>>>(joint, sums);
    fused_kernel<<<FUSED_BLOCKS, TPB, 0, stream>>>(
        (const int4*)fl, (const int4*)ml, joint, (const float4*)vf, sums);
    finalize_kernel<<<1, 64, 0, stream>>>(joint, sums, out);
}